// Round 5
// baseline (157.401 us; speedup 1.0000x reference)
//
#include <hip/hip_runtime.h>
#include <hip/hip_bf16.h>

typedef unsigned short u16;
typedef __bf16 bf16x8 __attribute__((ext_vector_type(8)));
typedef float f32x4 __attribute__((ext_vector_type(4)));

#define DEVINL __device__ __forceinline__

static constexpr int Bc = 8, Tc = 2048;

DEVINL u16 f2bf(float f) {
  unsigned u = __builtin_bit_cast(unsigned, f);
  unsigned r = u + 0x7fffu + ((u >> 16) & 1u);   // RNE
  return (u16)(r >> 16);
}
DEVINL float bf2f(u16 h) {
  unsigned u = ((unsigned)h) << 16;
  return __builtin_bit_cast(float, u);
}

// swizzled LDS read of 8 contiguous bf16 from a [R][64] bf16 tile.
DEVINL bf16x8 lds_ld8(const u16* p, int row, int col) {
  return *(const bf16x8*)&p[row * 64 + (col ^ ((row & 7) << 3))];
}

// ---------------------------------------------------------------------------
// Kernel 0: wt_{hi,lo}[c][k] = split(W_{c/64}[k][c%64]), c in [0,192)
// ---------------------------------------------------------------------------
__global__ __launch_bounds__(256) void build_wt(const float* __restrict__ Wk,
                                                const float* __restrict__ Wq,
                                                const float* __restrict__ Wv,
                                                u16* __restrict__ wt_hi,
                                                u16* __restrict__ wt_lo) {
  int idx = blockIdx.x * 256 + threadIdx.x;      // 192*1024
  int c = idx >> 10, k = idx & 1023;
  const float* W = (c < 64) ? Wk : (c < 128 ? Wq : Wv);
  float f = W[k * 64 + (c & 63)];
  u16 h = f2bf(f);
  wt_hi[idx] = h;
  wt_lo[idx] = f2bf(f - bf2f(h));
}

// ---------------------------------------------------------------------------
// Kernel 1: fused QKV projection, hi/lo split. 512 blocks x 512 thr (8 waves).
// 32 rows/block; wave w: rowset w>>2, col-tiles (w&3)*3..+2.
// V written TRANSPOSED [b][d][t].
// ---------------------------------------------------------------------------
__global__ __launch_bounds__(512) void proj_kernel(const float* __restrict__ x,
                                                   const u16* __restrict__ wt_hi,
                                                   const u16* __restrict__ wt_lo,
                                                   u16* __restrict__ kb_h, u16* __restrict__ kb_l,
                                                   u16* __restrict__ qb_h, u16* __restrict__ qb_l,
                                                   u16* __restrict__ vt) {
  __shared__ u16 xh[2][32 * 64];
  __shared__ u16 xl[2][32 * 64];
  const int t = threadIdx.x;
  const int w = t >> 6, lane = t & 63;
  const int l16 = lane & 15, lhi = lane >> 4;
  const int rb = blockIdx.x * 32;
  const int rs = w >> 2;                 // rowset 0/1
  const int ct3 = (w & 3) * 3;           // first of 3 col-tiles
  const int sr = t >> 4, sc4 = (t & 15) * 4;
  const float* xrow = x + (size_t)(rb + sr) * 1024 + sc4;

  f32x4 acc[3];
#pragma unroll
  for (int c = 0; c < 3; ++c) acc[c] = (f32x4){0.f, 0.f, 0.f, 0.f};

#define CVT_STORE(S, F)                                                        \
  {                                                                            \
    union { u16 u[4]; uint2 v; } ph_, pl_;                                     \
    _Pragma("unroll") for (int j = 0; j < 4; ++j) {                            \
      u16 h0 = f2bf((F)[j]); ph_.u[j] = h0; pl_.u[j] = f2bf((F)[j] - bf2f(h0)); \
    }                                                                          \
    *(uint2*)&xh[S][sr * 64 + (sc4 ^ ((sr & 7) << 3))] = ph_.v;                \
    *(uint2*)&xl[S][sr * 64 + (sc4 ^ ((sr & 7) << 3))] = pl_.v;                \
  }

#define COMPUTE(S, CH)                                                         \
  _Pragma("unroll") for (int kk = 0; kk < 2; ++kk) {                           \
    bf16x8 ah = lds_ld8(xh[S], rs * 16 + l16, kk * 32 + lhi * 8);              \
    bf16x8 al = lds_ld8(xl[S], rs * 16 + l16, kk * 32 + lhi * 8);              \
    _Pragma("unroll") for (int tc = 0; tc < 3; ++tc) {                         \
      size_t wi = (size_t)((ct3 + tc) * 16 + l16) * 1024 + (CH) * 64 + kk * 32 + lhi * 8; \
      bf16x8 bh = *(const bf16x8*)&wt_hi[wi];                                  \
      bf16x8 bl = *(const bf16x8*)&wt_lo[wi];                                  \
      acc[tc] = __builtin_amdgcn_mfma_f32_16x16x32_bf16(ah, bh, acc[tc], 0, 0, 0); \
      acc[tc] = __builtin_amdgcn_mfma_f32_16x16x32_bf16(ah, bl, acc[tc], 0, 0, 0); \
      acc[tc] = __builtin_amdgcn_mfma_f32_16x16x32_bf16(al, bh, acc[tc], 0, 0, 0); \
    }                                                                          \
  }

  // prologue: 2-deep prefetch
  f32x4 A = *(const f32x4*)(xrow);
  f32x4 B = *(const f32x4*)(xrow + 64);
  CVT_STORE(0, A);
  __syncthreads();

  for (int i = 0; i < 8; ++i) {
    const int ch = 2 * i;
    if (ch + 2 < 16) A = *(const f32x4*)(xrow + (ch + 2) * 64);
    COMPUTE(0, ch);
    CVT_STORE(1, B);
    __syncthreads();
    if (ch + 3 < 16) B = *(const f32x4*)(xrow + (ch + 3) * 64);
    COMPUTE(1, ch + 1);
    if (ch + 2 < 16) { CVT_STORE(0, A); __syncthreads(); }
  }
#undef CVT_STORE
#undef COMPUTE

  // epilogue
#pragma unroll
  for (int tc = 0; tc < 3; ++tc) {
    int gc = (ct3 + tc) * 16 + l16;
    int cc = gc & 63;
    int row = rb + rs * 16 + lhi * 4;
#pragma unroll
    for (int i = 0; i < 4; ++i) {
      float f = acc[tc][i];
      int r = row + i;
      u16 h = f2bf(f);
      if (gc < 64) {
        size_t off = (size_t)r * 64 + cc;
        kb_h[off] = h; kb_l[off] = f2bf(f - bf2f(h));
      } else if (gc < 128) {
        size_t off = (size_t)r * 64 + cc;
        qb_h[off] = h; qb_l[off] = f2bf(f - bf2f(h));
      } else {
        int bb = r >> 11, tp = r & 2047;
        vt[((size_t)bb * 64 + cc) * 2048 + tp] = h;
      }
    }
  }
}

// ---------------------------------------------------------------------------
// Kernel 2: causal flash attention, barrier-free, KV-chunk 512.
// 160 units/batch x 8 = 1280 blocks x 1 wave. All units write (O,m,l)
// partials; combine merges. Register-light: K frags per-t4 transient.
// Unit map (u in [0,160)): c=0:u<64 j=63-u; c=1:u<112 j=63-(u-64);
//                          c=2:u<144 j=63-(u-112); c=3: j=63-(u-144).
// ---------------------------------------------------------------------------
__global__ __launch_bounds__(64, 2) void attn_kernel(const u16* __restrict__ qb_h,
                                                     const u16* __restrict__ qb_l,
                                                     const u16* __restrict__ kb_h,
                                                     const u16* __restrict__ kb_l,
                                                     const u16* __restrict__ vt,
                                                     float* __restrict__ po,
                                                     float* __restrict__ pml) {
  __shared__ u16 p_l[2][1024];           // per-rowset P tile (16x64, swizzled)

  const int t = threadIdx.x;             // one wave
  const int l16 = t & 15, lhi = t >> 4;
  const int u = blockIdx.x >> 3, b = blockIdx.x & 7;

  int j, c;
  if (u < 64)       { c = 0; j = 63 - u; }
  else if (u < 112) { c = 1; j = 63 - (u - 64); }
  else if (u < 144) { c = 2; j = 63 - (u - 112); }
  else              { c = 3; j = 63 - (u - 144); }

  const int kv0 = c << 9;
  const int prefix = j * 32 + 32;
  const int kv_end = (prefix < kv0 + 512) ? prefix : (kv0 + 512);
  const int nt = (kv_end - kv0 + 63) >> 6;
  const bool diag = (kv_end == prefix);

  const size_t qrow = (size_t)b * 2048 + j * 32;

  // Q fragments straight from global: lane l16 = q row, 16B contiguous cols
  bf16x8 aqh[2][2], aql[2][2];           // [rowset][kk]
#pragma unroll
  for (int rs = 0; rs < 2; ++rs)
#pragma unroll
    for (int kk = 0; kk < 2; ++kk) {
      size_t qo = (qrow + rs * 16 + l16) * 64 + kk * 32 + lhi * 8;
      aqh[rs][kk] = *(const bf16x8*)(qb_h + qo);
      aql[rs][kk] = *(const bf16x8*)(qb_l + qo);
    }

  f32x4 o[2][4];
  float m_r[2][4], l_r[2][4];
#pragma unroll
  for (int rs = 0; rs < 2; ++rs)
#pragma unroll
    for (int i = 0; i < 4; ++i) {
      o[rs][i] = (f32x4){0.f, 0.f, 0.f, 0.f};
      m_r[rs][i] = -3.0e38f; l_r[rs][i] = 0.f;
    }

  for (int tk = 0; tk < nt; ++tk) {
    const int kvb = kv0 + tk * 64;
    const size_t kbase = ((size_t)b * 2048 + kvb) * 64;

    // S = Q K^T: K frags loaded per-t4 (transient regs)
    f32x4 sa[2][4];
#pragma unroll
    for (int t4 = 0; t4 < 4; ++t4) {
      size_t kr = kbase + (size_t)(t4 * 16 + l16) * 64 + lhi * 8;
      bf16x8 kh0 = *(const bf16x8*)(kb_h + kr);
      bf16x8 kh1 = *(const bf16x8*)(kb_h + kr + 32);
      bf16x8 kl0 = *(const bf16x8*)(kb_l + kr);
      bf16x8 kl1 = *(const bf16x8*)(kb_l + kr + 32);
#pragma unroll
      for (int rs = 0; rs < 2; ++rs) {
        f32x4 s = (f32x4){0.f, 0.f, 0.f, 0.f};
        s = __builtin_amdgcn_mfma_f32_16x16x32_bf16(aqh[rs][0], kh0, s, 0, 0, 0);
        s = __builtin_amdgcn_mfma_f32_16x16x32_bf16(aqh[rs][0], kl0, s, 0, 0, 0);
        s = __builtin_amdgcn_mfma_f32_16x16x32_bf16(aql[rs][0], kh0, s, 0, 0, 0);
        s = __builtin_amdgcn_mfma_f32_16x16x32_bf16(aqh[rs][1], kh1, s, 0, 0, 0);
        s = __builtin_amdgcn_mfma_f32_16x16x32_bf16(aqh[rs][1], kl1, s, 0, 0, 0);
        s = __builtin_amdgcn_mfma_f32_16x16x32_bf16(aql[rs][1], kh1, s, 0, 0, 0);
        sa[rs][t4] = s;
      }
    }

    // V fragment loads (consumed in PV; issued before softmax to hide latency)
    bf16x8 vv[4][2];
#pragma unroll
    for (int t4 = 0; t4 < 4; ++t4) {
      size_t vr = ((size_t)b * 64 + t4 * 16 + l16) * 2048 + kvb + lhi * 8;
      vv[t4][0] = *(const bf16x8*)(vt + vr);
      vv[t4][1] = *(const bf16x8*)(vt + vr + 32);
    }

    // causal mask (global indices); only the diagonal unit's last tile
    if (diag && tk == nt - 1) {
#pragma unroll
      for (int rs = 0; rs < 2; ++rs) {
        int qr = j * 32 + rs * 16 + lhi * 4;
#pragma unroll
        for (int t4 = 0; t4 < 4; ++t4) {
          int col = kvb + t4 * 16 + l16;
#pragma unroll
          for (int i = 0; i < 4; ++i)
            if (col > qr + i) sa[rs][t4][i] = -1e30f;
        }
      }
    }

#pragma unroll
    for (int rs = 0; rs < 2; ++rs) {
      // online softmax
      float pf[4][4];
#pragma unroll
      for (int i = 0; i < 4; ++i) {
        float tm = fmaxf(fmaxf(sa[rs][0][i], sa[rs][1][i]), fmaxf(sa[rs][2][i], sa[rs][3][i]));
#pragma unroll
        for (int d = 1; d < 16; d <<= 1) tm = fmaxf(tm, __shfl_xor(tm, d));
        float mn = fmaxf(m_r[rs][i], tm);
        float scl = __expf(m_r[rs][i] - mn);
        float rsum = 0.f;
#pragma unroll
        for (int t4 = 0; t4 < 4; ++t4) {
          float p = __expf(sa[rs][t4][i] - mn);
          pf[t4][i] = p;
          rsum += p;
        }
#pragma unroll
        for (int d = 1; d < 16; d <<= 1) rsum += __shfl_xor(rsum, d);
        l_r[rs][i] = l_r[rs][i] * scl + rsum;
        m_r[rs][i] = mn;
#pragma unroll
        for (int t4 = 0; t4 < 4; ++t4) o[rs][t4][i] *= scl;
      }

      // P -> bf16 -> per-rowset LDS (swizzled, wave-private, no barrier)
      u16* pw = (u16*)p_l[rs];
#pragma unroll
      for (int i = 0; i < 4; ++i) {
        int rr = lhi * 4 + i;
#pragma unroll
        for (int t4 = 0; t4 < 4; ++t4) {
          int col = t4 * 16 + l16;
          pw[rr * 64 + (col ^ ((rr & 7) << 3))] = f2bf(pf[t4][i]);
        }
      }
      // PV
#pragma unroll
      for (int kk = 0; kk < 2; ++kk) {
        bf16x8 ap = lds_ld8(pw, l16, kk * 32 + lhi * 8);
#pragma unroll
        for (int t4 = 0; t4 < 4; ++t4)
          o[rs][t4] = __builtin_amdgcn_mfma_f32_16x16x32_bf16(ap, vv[t4][kk], o[rs][t4], 0, 0, 0);
      }
    }
  }

  // write partials (all units)
  const int slot = blockIdx.x;
  float* pou = po + (size_t)slot * 2048;
#pragma unroll
  for (int rs = 0; rs < 2; ++rs)
#pragma unroll
    for (int t4 = 0; t4 < 4; ++t4) {
      int col = t4 * 16 + l16;
#pragma unroll
      for (int i = 0; i < 4; ++i)
        pou[(rs * 16 + lhi * 4 + i) * 64 + col] = o[rs][t4][i];
    }
  if (l16 == 0) {
#pragma unroll
    for (int rs = 0; rs < 2; ++rs)
#pragma unroll
      for (int i = 0; i < 4; ++i) {
        int r = rs * 16 + lhi * 4 + i;
        pml[slot * 64 + r]      = m_r[rs][i];
        pml[slot * 64 + 32 + r] = l_r[rs][i];
      }
  }
}

// ---------------------------------------------------------------------------
// Kernel 3: merge up to 4 KV-chunk partials. Grid 512 = 64 j x 8 b, 256 thr.
// ---------------------------------------------------------------------------
__global__ __launch_bounds__(256) void combine_kernel(const float* __restrict__ po,
                                                      const float* __restrict__ pml,
                                                      float* __restrict__ out) {
  const int b = blockIdx.x & 7, j = blockIdx.x >> 3;
  const int nu = (j >> 4) + 1;
  const int s0 = ((0)   + 63 - j) * 8 + b;
  const int s1 = ((64)  + 63 - j) * 8 + b;
  const int s2 = ((112) + 63 - j) * 8 + b;
  const int s3 = ((144) + 63 - j) * 8 + b;
  float* og = out + ((size_t)b * 2048 + j * 32) * 64;
#pragma unroll
  for (int k = 0; k < 8; ++k) {
    int e = k * 256 + threadIdx.x;
    int r = e >> 6;
    float M = pml[s0 * 64 + r];
    if (nu > 1) M = fmaxf(M, pml[s1 * 64 + r]);
    if (nu > 2) M = fmaxf(M, pml[s2 * 64 + r]);
    if (nu > 3) M = fmaxf(M, pml[s3 * 64 + r]);
    float num, den;
    {
      float a = __expf(pml[s0 * 64 + r] - M);
      num = po[(size_t)s0 * 2048 + e] * a;
      den = pml[s0 * 64 + 32 + r] * a;
    }
    if (nu > 1) {
      float a = __expf(pml[s1 * 64 + r] - M);
      num += po[(size_t)s1 * 2048 + e] * a;
      den += pml[s1 * 64 + 32 + r] * a;
    }
    if (nu > 2) {
      float a = __expf(pml[s2 * 64 + r] - M);
      num += po[(size_t)s2 * 2048 + e] * a;
      den += pml[s2 * 64 + 32 + r] * a;
    }
    if (nu > 3) {
      float a = __expf(pml[s3 * 64 + r] - M);
      num += po[(size_t)s3 * 2048 + e] * a;
      den += pml[s3 * 64 + 32 + r] * a;
    }
    og[e] = num / den;
  }
}

// ---------------------------------------------------------------------------
extern "C" void kernel_launch(void* const* d_in, const int* in_sizes, int n_in,
                              void* d_out, int out_size, void* d_ws, size_t ws_size,
                              hipStream_t stream) {
  const float* x  = (const float*)d_in[0];
  const float* Wk = (const float*)d_in[1];
  const float* Wq = (const float*)d_in[2];
  const float* Wv = (const float*)d_in[3];
  float* out = (float*)d_out;

  const size_t QKV = (size_t)Bc * Tc * 64;       // 1,048,576 elems
  char* w = (char*)d_ws;
  u16* kb_h = (u16*)w;               w += QKV * 2;
  u16* kb_l = (u16*)w;               w += QKV * 2;
  u16* qb_h = (u16*)w;               w += QKV * 2;
  u16* qb_l = (u16*)w;               w += QKV * 2;
  u16* vt   = (u16*)w;               w += QKV * 2;
  u16* wt_h = (u16*)w;               w += (size_t)192 * 1024 * 2;
  u16* wt_l = (u16*)w;               w += (size_t)192 * 1024 * 2;
  float* po = (float*)w;             w += (size_t)1280 * 2048 * 4;
  float* pml = (float*)w;            w += (size_t)1280 * 64 * 4;

  build_wt<<<768, 256, 0, stream>>>(Wk, Wq, Wv, wt_h, wt_l);
  proj_kernel<<<512, 512, 0, stream>>>(x, wt_h, wt_l, kb_h, kb_l, qb_h, qb_l, vt);
  attn_kernel<<<1280, 64, 0, stream>>>(qb_h, qb_l, kb_h, kb_l, vt, po, pml);
  combine_kernel<<<512, 256, 0, stream>>>(po, pml, out);
}

// Round 6
// 116.031 us; speedup vs baseline: 1.3565x; 1.3565x over previous
//
#include <hip/hip_runtime.h>
#include <hip/hip_bf16.h>

typedef unsigned short u16;
typedef __bf16 bf16x8 __attribute__((ext_vector_type(8)));
typedef float f32x4 __attribute__((ext_vector_type(4)));

#define DEVINL __device__ __forceinline__

static constexpr int Bc = 8, Tc = 2048;

DEVINL u16 f2bf(float f) {
  unsigned u = __builtin_bit_cast(unsigned, f);
  unsigned r = u + 0x7fffu + ((u >> 16) & 1u);   // RNE
  return (u16)(r >> 16);
}
DEVINL float bf2f(u16 h) {
  unsigned u = ((unsigned)h) << 16;
  return __builtin_bit_cast(float, u);
}

// swizzled LDS read of 8 contiguous bf16 from a [R][64] bf16 tile.
DEVINL bf16x8 lds_ld8(const u16* p, int row, int col) {
  return *(const bf16x8*)&p[row * 64 + (col ^ ((row & 7) << 3))];
}

// ---------------------------------------------------------------------------
// Kernel 0: wt_{hi,lo}[c][k] = split(W_{c/64}[k][c%64]), c in [0,192)
// ---------------------------------------------------------------------------
__global__ __launch_bounds__(256) void build_wt(const float* __restrict__ Wk,
                                                const float* __restrict__ Wq,
                                                const float* __restrict__ Wv,
                                                u16* __restrict__ wt_hi,
                                                u16* __restrict__ wt_lo) {
  int idx = blockIdx.x * 256 + threadIdx.x;      // 192*1024
  int c = idx >> 10, k = idx & 1023;
  const float* W = (c < 64) ? Wk : (c < 128 ? Wq : Wv);
  float f = W[k * 64 + (c & 63)];
  u16 h = f2bf(f);
  wt_hi[idx] = h;
  wt_lo[idx] = f2bf(f - bf2f(h));
}

// ---------------------------------------------------------------------------
// Kernel 1: fused QKV projection, hi/lo split. R4 shape: 512 blocks x 256 thr
// (4 waves; wave w covers 48 cols x 32 rows). Changes vs R4:
//  - x loads NON-TEMPORAL (streaming x was evicting wt from L2 -> B-fragment
//    loads paid L3/HBM latency on the MFMA critical path)
//  - all 12 wt B-fragments of a chunk hoisted into registers up-front (one
//    latency exposure per chunk amortized over 36 MFMAs)
// V written TRANSPOSED [b][d][t].
// ---------------------------------------------------------------------------
__global__ __launch_bounds__(256, 2) void proj_kernel(const float* __restrict__ x,
                                                      const u16* __restrict__ wt_hi,
                                                      const u16* __restrict__ wt_lo,
                                                      u16* __restrict__ kb_h, u16* __restrict__ kb_l,
                                                      u16* __restrict__ qb_h, u16* __restrict__ qb_l,
                                                      u16* __restrict__ vt) {
  __shared__ u16 xh[2][32 * 64];
  __shared__ u16 xl[2][32 * 64];
  const int t = threadIdx.x;
  const int w = t >> 6, lane = t & 63;
  const int l16 = lane & 15, lhi = lane >> 4;
  const int rb = blockIdx.x * 32;
  const int cb = w * 48;
  const int sr = t >> 3, sc = (t & 7) * 8;
  const f32x4* xrow = (const f32x4*)(x + (size_t)(rb + sr) * 1024 + sc);
  // xrow stride in f32x4 units: 1024/4 = 256 per chunk-of-64? No: chunk step
  // is 64 floats = 16 f32x4; within-chunk second vec at +1.
  // index: chunk ch -> xrow[ch*16] and xrow[ch*16+1].

  f32x4 acc[2][3];
#pragma unroll
  for (int a = 0; a < 2; ++a)
#pragma unroll
    for (int c = 0; c < 3; ++c) acc[a][c] = (f32x4){0.f, 0.f, 0.f, 0.f};

#define CVT_STORE(S, F0, F1)                                                   \
  {                                                                            \
    union { u16 u[8]; uint4 v; } ph_, pl_;                                     \
    _Pragma("unroll") for (int j = 0; j < 4; ++j) {                            \
      u16 h0 = f2bf((F0)[j]); ph_.u[j] = h0; pl_.u[j] = f2bf((F0)[j] - bf2f(h0)); \
      u16 h1 = f2bf((F1)[j]); ph_.u[4+j] = h1; pl_.u[4+j] = f2bf((F1)[j] - bf2f(h1)); \
    }                                                                          \
    *(uint4*)&xh[S][sr * 64 + (sc ^ ((sr & 7) << 3))] = ph_.v;                 \
    *(uint4*)&xl[S][sr * 64 + (sc ^ ((sr & 7) << 3))] = pl_.v;                 \
  }

#define COMPUTE(S, CH)                                                         \
  {                                                                            \
    bf16x8 Bh_[2][3], Bl_[2][3];                                               \
    _Pragma("unroll") for (int kk = 0; kk < 2; ++kk)                           \
      _Pragma("unroll") for (int tc = 0; tc < 3; ++tc) {                       \
        size_t wi = (size_t)(cb + tc * 16 + l16) * 1024 + (CH) * 64 + kk * 32 + lhi * 8; \
        Bh_[kk][tc] = *(const bf16x8*)&wt_hi[wi];                              \
        Bl_[kk][tc] = *(const bf16x8*)&wt_lo[wi];                              \
      }                                                                        \
    _Pragma("unroll") for (int kk = 0; kk < 2; ++kk) {                         \
      bf16x8 a0h = lds_ld8(xh[S], l16, kk * 32 + lhi * 8);                     \
      bf16x8 a0l = lds_ld8(xl[S], l16, kk * 32 + lhi * 8);                     \
      bf16x8 a1h = lds_ld8(xh[S], 16 + l16, kk * 32 + lhi * 8);                \
      bf16x8 a1l = lds_ld8(xl[S], 16 + l16, kk * 32 + lhi * 8);                \
      _Pragma("unroll") for (int tc = 0; tc < 3; ++tc) {                       \
        acc[0][tc] = __builtin_amdgcn_mfma_f32_16x16x32_bf16(a0h, Bh_[kk][tc], acc[0][tc], 0, 0, 0); \
        acc[0][tc] = __builtin_amdgcn_mfma_f32_16x16x32_bf16(a0h, Bl_[kk][tc], acc[0][tc], 0, 0, 0); \
        acc[0][tc] = __builtin_amdgcn_mfma_f32_16x16x32_bf16(a0l, Bh_[kk][tc], acc[0][tc], 0, 0, 0); \
        acc[1][tc] = __builtin_amdgcn_mfma_f32_16x16x32_bf16(a1h, Bh_[kk][tc], acc[1][tc], 0, 0, 0); \
        acc[1][tc] = __builtin_amdgcn_mfma_f32_16x16x32_bf16(a1h, Bl_[kk][tc], acc[1][tc], 0, 0, 0); \
        acc[1][tc] = __builtin_amdgcn_mfma_f32_16x16x32_bf16(a1l, Bh_[kk][tc], acc[1][tc], 0, 0, 0); \
      }                                                                        \
    }                                                                          \
  }

  // prologue: 2-deep prefetch (non-temporal: x is read-once, keep it out of L2)
  f32x4 A0 = __builtin_nontemporal_load(xrow);
  f32x4 A1 = __builtin_nontemporal_load(xrow + 1);
  f32x4 B0 = __builtin_nontemporal_load(xrow + 16);
  f32x4 B1 = __builtin_nontemporal_load(xrow + 17);
  CVT_STORE(0, A0, A1);
  __syncthreads();

  for (int i = 0; i < 8; ++i) {
    const int ch = 2 * i;
    if (ch + 2 < 16) {
      A0 = __builtin_nontemporal_load(xrow + (ch + 2) * 16);
      A1 = __builtin_nontemporal_load(xrow + (ch + 2) * 16 + 1);
    }
    COMPUTE(0, ch);
    CVT_STORE(1, B0, B1);
    __syncthreads();
    if (ch + 3 < 16) {
      B0 = __builtin_nontemporal_load(xrow + (ch + 3) * 16);
      B1 = __builtin_nontemporal_load(xrow + (ch + 3) * 16 + 1);
    }
    COMPUTE(1, ch + 1);
    if (ch + 2 < 16) { CVT_STORE(0, A0, A1); __syncthreads(); }
  }
#undef CVT_STORE
#undef COMPUTE

  // epilogue
#pragma unroll
  for (int ri = 0; ri < 2; ++ri) {
#pragma unroll
    for (int tc = 0; tc < 3; ++tc) {
      int gc = cb + tc * 16 + l16;
      int cc = gc & 63;
      int row = rb + ri * 16 + lhi * 4;
#pragma unroll
      for (int i = 0; i < 4; ++i) {
        float f = acc[ri][tc][i];
        int r = row + i;
        u16 h = f2bf(f);
        if (gc < 64) {
          size_t off = (size_t)r * 64 + cc;
          kb_h[off] = h; kb_l[off] = f2bf(f - bf2f(h));
        } else if (gc < 128) {
          size_t off = (size_t)r * 64 + cc;
          qb_h[off] = h; qb_l[off] = f2bf(f - bf2f(h));
        } else {
          int bb = r >> 11, tp = r & 2047;
          vt[((size_t)bb * 64 + cc) * 2048 + tp] = h;
        }
      }
    }
  }
}

// ---------------------------------------------------------------------------
// Kernel 2: causal flash attention, barrier-free, KV-chunk 512. (unchanged R5)
// ---------------------------------------------------------------------------
__global__ __launch_bounds__(64, 2) void attn_kernel(const u16* __restrict__ qb_h,
                                                     const u16* __restrict__ qb_l,
                                                     const u16* __restrict__ kb_h,
                                                     const u16* __restrict__ kb_l,
                                                     const u16* __restrict__ vt,
                                                     float* __restrict__ po,
                                                     float* __restrict__ pml) {
  __shared__ u16 p_l[2][1024];           // per-rowset P tile (16x64, swizzled)

  const int t = threadIdx.x;             // one wave
  const int l16 = t & 15, lhi = t >> 4;
  const int u = blockIdx.x >> 3, b = blockIdx.x & 7;

  int j, c;
  if (u < 64)       { c = 0; j = 63 - u; }
  else if (u < 112) { c = 1; j = 63 - (u - 64); }
  else if (u < 144) { c = 2; j = 63 - (u - 112); }
  else              { c = 3; j = 63 - (u - 144); }

  const int kv0 = c << 9;
  const int prefix = j * 32 + 32;
  const int kv_end = (prefix < kv0 + 512) ? prefix : (kv0 + 512);
  const int nt = (kv_end - kv0 + 63) >> 6;
  const bool diag = (kv_end == prefix);

  const size_t qrow = (size_t)b * 2048 + j * 32;

  // Q fragments straight from global: lane l16 = q row, 16B contiguous cols
  bf16x8 aqh[2][2], aql[2][2];           // [rowset][kk]
#pragma unroll
  for (int rs = 0; rs < 2; ++rs)
#pragma unroll
    for (int kk = 0; kk < 2; ++kk) {
      size_t qo = (qrow + rs * 16 + l16) * 64 + kk * 32 + lhi * 8;
      aqh[rs][kk] = *(const bf16x8*)(qb_h + qo);
      aql[rs][kk] = *(const bf16x8*)(qb_l + qo);
    }

  f32x4 o[2][4];
  float m_r[2][4], l_r[2][4];
#pragma unroll
  for (int rs = 0; rs < 2; ++rs)
#pragma unroll
    for (int i = 0; i < 4; ++i) {
      o[rs][i] = (f32x4){0.f, 0.f, 0.f, 0.f};
      m_r[rs][i] = -3.0e38f; l_r[rs][i] = 0.f;
    }

  for (int tk = 0; tk < nt; ++tk) {
    const int kvb = kv0 + tk * 64;
    const size_t kbase = ((size_t)b * 2048 + kvb) * 64;

    // S = Q K^T: K frags loaded per-t4 (transient regs)
    f32x4 sa[2][4];
#pragma unroll
    for (int t4 = 0; t4 < 4; ++t4) {
      size_t kr = kbase + (size_t)(t4 * 16 + l16) * 64 + lhi * 8;
      bf16x8 kh0 = *(const bf16x8*)(kb_h + kr);
      bf16x8 kh1 = *(const bf16x8*)(kb_h + kr + 32);
      bf16x8 kl0 = *(const bf16x8*)(kb_l + kr);
      bf16x8 kl1 = *(const bf16x8*)(kb_l + kr + 32);
#pragma unroll
      for (int rs = 0; rs < 2; ++rs) {
        f32x4 s = (f32x4){0.f, 0.f, 0.f, 0.f};
        s = __builtin_amdgcn_mfma_f32_16x16x32_bf16(aqh[rs][0], kh0, s, 0, 0, 0);
        s = __builtin_amdgcn_mfma_f32_16x16x32_bf16(aqh[rs][0], kl0, s, 0, 0, 0);
        s = __builtin_amdgcn_mfma_f32_16x16x32_bf16(aql[rs][0], kh0, s, 0, 0, 0);
        s = __builtin_amdgcn_mfma_f32_16x16x32_bf16(aqh[rs][1], kh1, s, 0, 0, 0);
        s = __builtin_amdgcn_mfma_f32_16x16x32_bf16(aqh[rs][1], kl1, s, 0, 0, 0);
        s = __builtin_amdgcn_mfma_f32_16x16x32_bf16(aql[rs][1], kh1, s, 0, 0, 0);
        sa[rs][t4] = s;
      }
    }

    // V fragment loads (consumed in PV; issued before softmax to hide latency)
    bf16x8 vv[4][2];
#pragma unroll
    for (int t4 = 0; t4 < 4; ++t4) {
      size_t vr = ((size_t)b * 64 + t4 * 16 + l16) * 2048 + kvb + lhi * 8;
      vv[t4][0] = *(const bf16x8*)(vt + vr);
      vv[t4][1] = *(const bf16x8*)(vt + vr + 32);
    }

    // causal mask (global indices); only the diagonal unit's last tile
    if (diag && tk == nt - 1) {
#pragma unroll
      for (int rs = 0; rs < 2; ++rs) {
        int qr = j * 32 + rs * 16 + lhi * 4;
#pragma unroll
        for (int t4 = 0; t4 < 4; ++t4) {
          int col = kvb + t4 * 16 + l16;
#pragma unroll
          for (int i = 0; i < 4; ++i)
            if (col > qr + i) sa[rs][t4][i] = -1e30f;
        }
      }
    }

#pragma unroll
    for (int rs = 0; rs < 2; ++rs) {
      // online softmax
      float pf[4][4];
#pragma unroll
      for (int i = 0; i < 4; ++i) {
        float tm = fmaxf(fmaxf(sa[rs][0][i], sa[rs][1][i]), fmaxf(sa[rs][2][i], sa[rs][3][i]));
#pragma unroll
        for (int d = 1; d < 16; d <<= 1) tm = fmaxf(tm, __shfl_xor(tm, d));
        float mn = fmaxf(m_r[rs][i], tm);
        float scl = __expf(m_r[rs][i] - mn);
        float rsum = 0.f;
#pragma unroll
        for (int t4 = 0; t4 < 4; ++t4) {
          float p = __expf(sa[rs][t4][i] - mn);
          pf[t4][i] = p;
          rsum += p;
        }
#pragma unroll
        for (int d = 1; d < 16; d <<= 1) rsum += __shfl_xor(rsum, d);
        l_r[rs][i] = l_r[rs][i] * scl + rsum;
        m_r[rs][i] = mn;
#pragma unroll
        for (int t4 = 0; t4 < 4; ++t4) o[rs][t4][i] *= scl;
      }

      // P -> bf16 -> per-rowset LDS (swizzled, wave-private, no barrier)
      u16* pw = (u16*)p_l[rs];
#pragma unroll
      for (int i = 0; i < 4; ++i) {
        int rr = lhi * 4 + i;
#pragma unroll
        for (int t4 = 0; t4 < 4; ++t4) {
          int col = t4 * 16 + l16;
          pw[rr * 64 + (col ^ ((rr & 7) << 3))] = f2bf(pf[t4][i]);
        }
      }
      // PV
#pragma unroll
      for (int kk = 0; kk < 2; ++kk) {
        bf16x8 ap = lds_ld8(pw, l16, kk * 32 + lhi * 8);
#pragma unroll
        for (int t4 = 0; t4 < 4; ++t4)
          o[rs][t4] = __builtin_amdgcn_mfma_f32_16x16x32_bf16(ap, vv[t4][kk], o[rs][t4], 0, 0, 0);
      }
    }
  }

  // write partials (all units)
  const int slot = blockIdx.x;
  float* pou = po + (size_t)slot * 2048;
#pragma unroll
  for (int rs = 0; rs < 2; ++rs)
#pragma unroll
    for (int t4 = 0; t4 < 4; ++t4) {
      int col = t4 * 16 + l16;
#pragma unroll
      for (int i = 0; i < 4; ++i)
        pou[(rs * 16 + lhi * 4 + i) * 64 + col] = o[rs][t4][i];
    }
  if (l16 == 0) {
#pragma unroll
    for (int rs = 0; rs < 2; ++rs)
#pragma unroll
      for (int i = 0; i < 4; ++i) {
        int r = rs * 16 + lhi * 4 + i;
        pml[slot * 64 + r]      = m_r[rs][i];
        pml[slot * 64 + 32 + r] = l_r[rs][i];
      }
  }
}

// ---------------------------------------------------------------------------
// Kernel 3: merge up to 4 KV-chunk partials. Grid 512 = 64 j x 8 b, 256 thr.
// ---------------------------------------------------------------------------
__global__ __launch_bounds__(256) void combine_kernel(const float* __restrict__ po,
                                                      const float* __restrict__ pml,
                                                      float* __restrict__ out) {
  const int b = blockIdx.x & 7, j = blockIdx.x >> 3;
  const int nu = (j >> 4) + 1;
  const int s0 = ((0)   + 63 - j) * 8 + b;
  const int s1 = ((64)  + 63 - j) * 8 + b;
  const int s2 = ((112) + 63 - j) * 8 + b;
  const int s3 = ((144) + 63 - j) * 8 + b;
  float* og = out + ((size_t)b * 2048 + j * 32) * 64;
#pragma unroll
  for (int k = 0; k < 8; ++k) {
    int e = k * 256 + threadIdx.x;
    int r = e >> 6;
    float M = pml[s0 * 64 + r];
    if (nu > 1) M = fmaxf(M, pml[s1 * 64 + r]);
    if (nu > 2) M = fmaxf(M, pml[s2 * 64 + r]);
    if (nu > 3) M = fmaxf(M, pml[s3 * 64 + r]);
    float num, den;
    {
      float a = __expf(pml[s0 * 64 + r] - M);
      num = po[(size_t)s0 * 2048 + e] * a;
      den = pml[s0 * 64 + 32 + r] * a;
    }
    if (nu > 1) {
      float a = __expf(pml[s1 * 64 + r] - M);
      num += po[(size_t)s1 * 2048 + e] * a;
      den += pml[s1 * 64 + 32 + r] * a;
    }
    if (nu > 2) {
      float a = __expf(pml[s2 * 64 + r] - M);
      num += po[(size_t)s2 * 2048 + e] * a;
      den += pml[s2 * 64 + 32 + r] * a;
    }
    if (nu > 3) {
      float a = __expf(pml[s3 * 64 + r] - M);
      num += po[(size_t)s3 * 2048 + e] * a;
      den += pml[s3 * 64 + 32 + r] * a;
    }
    og[e] = num / den;
  }
}

// ---------------------------------------------------------------------------
extern "C" void kernel_launch(void* const* d_in, const int* in_sizes, int n_in,
                              void* d_out, int out_size, void* d_ws, size_t ws_size,
                              hipStream_t stream) {
  const float* x  = (const float*)d_in[0];
  const float* Wk = (const float*)d_in[1];
  const float* Wq = (const float*)d_in[2];
  const float* Wv = (const float*)d_in[3];
  float* out = (float*)d_out;

  const size_t QKV = (size_t)Bc * Tc * 64;       // 1,048,576 elems
  char* w = (char*)d_ws;
  u16* kb_h = (u16*)w;               w += QKV * 2;
  u16* kb_l = (u16*)w;               w += QKV * 2;
  u16* qb_h = (u16*)w;               w += QKV * 2;
  u16* qb_l = (u16*)w;               w += QKV * 2;
  u16* vt   = (u16*)w;               w += QKV * 2;
  u16* wt_h = (u16*)w;               w += (size_t)192 * 1024 * 2;
  u16* wt_l = (u16*)w;               w += (size_t)192 * 1024 * 2;
  float* po = (float*)w;             w += (size_t)1280 * 2048 * 4;
  float* pml = (float*)w;            w += (size_t)1280 * 64 * 4;

  build_wt<<<768, 256, 0, stream>>>(Wk, Wq, Wv, wt_h, wt_l);
  proj_kernel<<<512, 256, 0, stream>>>(x, wt_h, wt_l, kb_h, kb_l, qb_h, qb_l, vt);
  attn_kernel<<<1280, 64, 0, stream>>>(qb_h, qb_l, kb_h, kb_l, vt, po, pml);
  combine_kernel<<<512, 256, 0, stream>>>(po, pml, out);
}